// Round 6
// baseline (238.268 us; speedup 1.0000x reference)
//
#include <hip/hip_runtime.h>

static constexpr int NROWS = 32768;
static constexpr int FIN   = 1024;
static constexpr int FOUT  = 512;
static constexpr int NREP  = 16;     // u accumulator groups (written by k2b)

// ws layout (~9.5 MB of the 512 MiB available):
//   double e[32768]        : unnormalized exp(scores)        (256 KB)
//   double hpart[1024]     : h[k] * (W@a1)[k]                (8 KB)
//   double zpart[1024]     : per-K2-block partial of Z       (8 KB)
//   float  v[1024]         : W @ a2                          (4 KB)
//   float  u16[16][1024]   : group-reduced u accumulators    (64 KB)
//   float  part[1024][1024]: per-block u partials            (4 MB)
//   float  dump[262144]    : probe sink (1 MB)
//
// d_out layout: [0:512) out fp32 | [512:33280) attention2 as 0.0/1.0

// ---------------------------------------------------------------------------
// K1: one wave per k (1024 waves). No atomics, no zeroing (k2b overwrites u16).
// ---------------------------------------------------------------------------
__global__ __launch_bounds__(256) void k1_prep(const float* __restrict__ W,
                                               const float* __restrict__ a,
                                               const float* __restrict__ h,
                                               float* __restrict__ v,
                                               double* __restrict__ hpart) {
    const int k    = (blockIdx.x * blockDim.x + threadIdx.x) >> 6;  // 0..1023
    const int lane = threadIdx.x & 63;

    const float4* Wrow = (const float4*)(W + (size_t)k * FOUT);
    float4 w0 = Wrow[lane];
    float4 w1 = Wrow[64 + lane];

    const float4* a4 = (const float4*)a;
    float4 a1_0 = a4[lane];
    float4 a1_1 = a4[64 + lane];
    float4 a2_0 = a4[128 + lane];
    float4 a2_1 = a4[192 + lane];

    double d1 = (double)w0.x * a1_0.x + (double)w0.y * a1_0.y +
                (double)w0.z * a1_0.z + (double)w0.w * a1_0.w +
                (double)w1.x * a1_1.x + (double)w1.y * a1_1.y +
                (double)w1.z * a1_1.z + (double)w1.w * a1_1.w;
    double d2 = (double)w0.x * a2_0.x + (double)w0.y * a2_0.y +
                (double)w0.z * a2_0.z + (double)w0.w * a2_0.w +
                (double)w1.x * a2_1.x + (double)w1.y * a2_1.y +
                (double)w1.z * a2_1.z + (double)w1.w * a2_1.w;

    #pragma unroll
    for (int off = 32; off; off >>= 1) {
        d1 += __shfl_xor(d1, off);
        d2 += __shfl_xor(d2, off);
    }
    if (lane == 0) {
        v[k]     = (float)d2;
        hpart[k] = (double)h[k] * d1;
    }
}

// ---------------------------------------------------------------------------
// K2: 1024 blocks x 256 threads (4096 waves, 8 rows/wave). Single adj pass.
// Batch-4 + privatized partials (rounds 4/5). UNCHANGED this round.
// ---------------------------------------------------------------------------
__global__ __launch_bounds__(256) void k2_main(const float* __restrict__ adj,
                                               const float* __restrict__ v,
                                               const double* __restrict__ hpart,
                                               double* __restrict__ e,
                                               float* __restrict__ part,  // [1024][1024]
                                               double* __restrict__ zpart) {
    __shared__ float  uls[4][1024];
    __shared__ double zls[4];

    const int wave  = threadIdx.x >> 6;               // 0..3
    const int lane  = threadIdx.x & 63;
    const int gwave = blockIdx.x * 4 + wave;          // 0..4095

    const int row0 = gwave * 8;
    const float4* base = (const float4*)(adj + (size_t)row0 * FIN) + lane;

    // ---- issue ALL 32 loads first (8 rows x 4 quarters, 16B each) ----
    float4 R0[16], R1[16];   // R0 = rows 0..3, R1 = rows 4..7; [r*4+q]
    #pragma unroll
    for (int r = 0; r < 4; ++r)
        #pragma unroll
        for (int q = 0; q < 4; ++q)
            R0[r * 4 + q] = base[r * 256 + q * 64];
    #pragma unroll
    for (int r = 0; r < 4; ++r)
        #pragma unroll
        for (int q = 0; q < 4; ++q)
            R1[r * 4 + q] = base[(4 + r) * 256 + q * 64];

    // c0 = sum(hpart), identical order in every wave -> bitwise-identical
    double c0 = 0.0;
    #pragma unroll
    for (int j = 0; j < 16; ++j) c0 += hpart[j * 64 + lane];
    #pragma unroll
    for (int off = 32; off; off >>= 1) c0 += __shfl_xor(c0, off);

    const float4* v4 = (const float4*)v;
    float4 vf[4];
    #pragma unroll
    for (int q = 0; q < 4; ++q) vf[q] = v4[q * 64 + lane];

    float  uacc[4][4] = {};
    double zacc = 0.0;   // wave-uniform

    auto do_batch4 = [&](const float4 (&buf)[16], const int rowb) {
        double d[4];
        #pragma unroll
        for (int r = 0; r < 4; ++r) {
            double dot = 0.0;
            #pragma unroll
            for (int q = 0; q < 4; ++q) {
                const float4 dd = buf[r * 4 + q];
                dot += (double)dd.x * vf[q].x + (double)dd.y * vf[q].y +
                       (double)dd.z * vf[q].z + (double)dd.w * vf[q].w;
            }
            d[r] = dot;
        }
        #pragma unroll
        for (int off = 32; off; off >>= 1) {
            #pragma unroll
            for (int r = 0; r < 4; ++r) d[r] += __shfl_xor(d[r], off);
        }

        double s[4];
        #pragma unroll
        for (int r = 0; r < 4; ++r) {
            s[r] = c0 + d[r];
            if (s[r] < 0.0) s[r] *= 0.1;     // leaky_relu(0.1)
        }

        const double sx = (lane & 32) ? ((lane & 16) ? s[3] : s[2])
                                      : ((lane & 16) ? s[1] : s[0]);
        const double evx = exp(sx);
        double ev[4];
        #pragma unroll
        for (int r = 0; r < 4; ++r) ev[r] = __shfl(evx, r * 16);

        #pragma unroll
        for (int r = 0; r < 4; ++r) zacc += ev[r];
        if (lane == 0) {
            #pragma unroll
            for (int r = 0; r < 4; ++r) e[rowb + r] = ev[r];
        }

        #pragma unroll
        for (int r = 0; r < 4; ++r) {
            const float evf = (float)ev[r];
            #pragma unroll
            for (int q = 0; q < 4; ++q) {
                const float4 dd = buf[r * 4 + q];
                uacc[q][0] += evf * dd.x;
                uacc[q][1] += evf * dd.y;
                uacc[q][2] += evf * dd.z;
                uacc[q][3] += evf * dd.w;
            }
        }
    };

    do_batch4(R0, row0);
    do_batch4(R1, row0 + 4);

    float4* uls4w = (float4*)&uls[wave][0];
    #pragma unroll
    for (int q = 0; q < 4; ++q)
        uls4w[q * 64 + lane] = make_float4(uacc[q][0], uacc[q][1], uacc[q][2], uacc[q][3]);

    if (lane == 0) zls[wave] = zacc;

    __syncthreads();

    const int t = threadIdx.x;
    const float4* uls4 = (const float4*)uls;
    float4 s0 = uls4[t];
    float4 s1 = uls4[256 + t];
    float4 s2 = uls4[512 + t];
    float4 s3 = uls4[768 + t];

    float4* prow = (float4*)(part + (size_t)blockIdx.x * 1024);
    prow[t] = make_float4(s0.x + s1.x + s2.x + s3.x,
                          s0.y + s1.y + s2.y + s3.y,
                          s0.z + s1.z + s2.z + s3.z,
                          s0.w + s1.w + s2.w + s3.w);

    if (t == 0) zpart[blockIdx.x] = zls[0] + zls[1] + zls[2] + zls[3];
}

// ---------------------------------------------------------------------------
// K2b: reduce part[1024][1024] -> u16[16][1024]. 64 blocks x 256 threads.
// ---------------------------------------------------------------------------
__global__ __launch_bounds__(256) void k2b_reduce(const float* __restrict__ part,
                                                  float* __restrict__ u16) {
    const int g   = blockIdx.x >> 2;          // 0..15
    const int c   = blockIdx.x & 3;           // 0..3
    const int col = c * 256 + threadIdx.x;    // 0..1023
    const float* p = part + (size_t)g * 64 * 1024 + col;
    float acc = 0.f;
    #pragma unroll 8
    for (int b = 0; b < 64; ++b) acc += p[(size_t)b * 1024];
    u16[g * 1024 + col] = acc;
}

// ---------------------------------------------------------------------------
// Deterministic Z from zpart (identical order in every block).
// ---------------------------------------------------------------------------
__device__ __forceinline__ double block_reduce_Z(const double* __restrict__ zpart,
                                                 double* zs) {
    const int t = threadIdx.x;
    zs[t] = zpart[t] + zpart[256 + t] + zpart[512 + t] + zpart[768 + t];
    __syncthreads();
    for (int st = 128; st > 0; st >>= 1) {
        if (t < st) zs[t] += zs[t + st];
        __syncthreads();
    }
    double Z = zs[0];
    __syncthreads();
    return Z;
}

// ---------------------------------------------------------------------------
// K3 (fused): blocks 0..15  -> out[0:512] = (u/Z) @ W1
//             blocks 16..31 -> out[512+i] = (N*e_i > Z) ? 1 : 0
// ---------------------------------------------------------------------------
__global__ __launch_bounds__(256) void k3_final(const double* __restrict__ e,
                                                const double* __restrict__ zpart,
                                                const float* __restrict__ u16,
                                                const float* __restrict__ W1,
                                                float* __restrict__ out) {
    __shared__ double zs[256];
    const double Z = block_reduce_Z(zpart, zs);
    const int t = threadIdx.x;

    if (blockIdx.x < 16) {
        __shared__ float us[1024];
        __shared__ float red[8][32];

        #pragma unroll
        for (int g = 0; g < 4; ++g) {
            const int k = g * 256 + t;
            float s = 0.f;
            #pragma unroll
            for (int rep = 0; rep < NREP; ++rep) s += u16[rep * 1024 + k];
            us[k] = s;
        }
        __syncthreads();

        const int cl  = t & 31;
        const int kg  = t >> 5;
        const int col = blockIdx.x * 32 + cl;
        float acc = 0.f;
        #pragma unroll 8
        for (int kk = 0; kk < 128; ++kk) {
            const int k = kg * 128 + kk;
            acc += us[k] * W1[(size_t)k * FOUT + col];
        }
        red[kg][cl] = acc;
        __syncthreads();
        if (t < 32) {
            float tot = 0.f;
            #pragma unroll
            for (int g = 0; g < 8; ++g) tot += red[g][t];
            out[blockIdx.x * 32 + t] = (float)((double)tot / Z);
        }
    } else {
        const int i0 = (blockIdx.x - 16) * 2048 + t * 8;
        const double2* e2 = (const double2*)(e + i0);
        const double thr = Z;
        float r[8];
        #pragma unroll
        for (int q = 0; q < 4; ++q) {
            double2 ev = e2[q];
            r[2 * q]     = (ev.x * (double)NROWS > thr) ? 1.0f : 0.0f;
            r[2 * q + 1] = (ev.y * (double)NROWS > thr) ? 1.0f : 0.0f;
        }
        float4* o4 = (float4*)(out + FOUT + i0);
        o4[0] = make_float4(r[0], r[1], r[2], r[3]);
        o4[1] = make_float4(r[4], r[5], r[6], r[7]);
    }
}

// ---------------------------------------------------------------------------
// K0_PROBE (measurement, round 6): pure adj stream with k2's EXACT grid,
// lane mapping, and 32-load pattern — no f64, no shuffles, no exp, no LDS.
// Launched LAST (adj is L3-warm, mirroring k2's best-case memory path).
// delta(total) = dur(probe) + ~2us gap:
//   probe ~10-25us -> memory path fine -> k2's 66us is serial-structure bound
//   probe ~50-70us -> pattern/request-rate limit -> k2 near its real floor
// Sink write keeps loads live; deterministic; outputs untouched.
// ---------------------------------------------------------------------------
__global__ __launch_bounds__(256) void k0_probe(const float* __restrict__ adj,
                                                float* __restrict__ dump) {
    const int wave  = threadIdx.x >> 6;
    const int lane  = threadIdx.x & 63;
    const int gwave = blockIdx.x * 4 + wave;
    const int row0  = gwave * 8;
    const float4* base = (const float4*)(adj + (size_t)row0 * FIN) + lane;

    // 4 independent f32 accumulator chains (one per quarter) -> loads pipeline
    float4 acc0 = make_float4(0.f, 0.f, 0.f, 0.f);
    float4 acc1 = acc0, acc2 = acc0, acc3 = acc0;
    #pragma unroll
    for (int r = 0; r < 8; ++r) {
        float4 d0 = base[r * 256];
        float4 d1 = base[r * 256 + 64];
        float4 d2 = base[r * 256 + 128];
        float4 d3 = base[r * 256 + 192];
        acc0.x += d0.x; acc0.y += d0.y; acc0.z += d0.z; acc0.w += d0.w;
        acc1.x += d1.x; acc1.y += d1.y; acc1.z += d1.z; acc1.w += d1.w;
        acc2.x += d2.x; acc2.y += d2.y; acc2.z += d2.z; acc2.w += d2.w;
        acc3.x += d3.x; acc3.y += d3.y; acc3.z += d3.z; acc3.w += d3.w;
    }
    dump[blockIdx.x * 256 + threadIdx.x] =
        (acc0.x + acc0.y + acc0.z + acc0.w) + (acc1.x + acc1.y + acc1.z + acc1.w) +
        (acc2.x + acc2.y + acc2.z + acc2.w) + (acc3.x + acc3.y + acc3.z + acc3.w);
}

extern "C" void kernel_launch(void* const* d_in, const int* in_sizes, int n_in,
                              void* d_out, int out_size, void* d_ws, size_t ws_size,
                              hipStream_t stream) {
    const float* h   = (const float*)d_in[0];   // (1, 1024)
    const float* adj = (const float*)d_in[1];   // (32768, 1024)
    const float* W   = (const float*)d_in[2];   // (1024, 512)
    const float* a   = (const float*)d_in[3];   // (1024, 1)
    const float* W1  = (const float*)d_in[4];   // (1024, 512)
    float* out = (float*)d_out;

    double* e     = (double*)d_ws;              // [32768]
    double* hpart = e + NROWS;                  // [1024]
    double* zpart = hpart + 1024;               // [1024]
    float*  v     = (float*)(zpart + 1024);     // [1024]
    float*  u16   = v + 1024;                   // [16][1024]
    float*  part  = u16 + 16 * 1024;            // [1024][1024]
    float*  dump  = part + 1024 * 1024;         // [262144]

    k1_prep<<<dim3(256),  dim3(256), 0, stream>>>(W, a, h, v, hpart);
    k2_main<<<dim3(1024), dim3(256), 0, stream>>>(adj, v, hpart, e, part, zpart);
    k2b_reduce<<<dim3(64), dim3(256), 0, stream>>>(part, u16);
    k3_final<<<dim3(32),  dim3(256), 0, stream>>>(e, zpart, u16, W1, out);
    k0_probe<<<dim3(1024), dim3(256), 0, stream>>>(adj, dump);   // measurement
}

// Round 7
// 217.061 us; speedup vs baseline: 1.0977x; 1.0977x over previous
//
#include <hip/hip_runtime.h>

static constexpr int NROWS = 32768;
static constexpr int FIN   = 1024;
static constexpr int FOUT  = 512;
static constexpr int NREP  = 16;     // u accumulator groups (written by k2b)

// ws layout (~4.4 MB of the 512 MiB available):
//   double e[32768]        : unnormalized exp(scores)        (256 KB)
//   double hpart[1024]     : h[k] * (W@a1)[k]                (8 KB)
//   double zpart[1024]     : per-K2-block partial of Z       (8 KB)
//   float  v[1024]         : W @ a2                          (4 KB)
//   float  u16[16][1024]   : group-reduced u accumulators    (64 KB)
//   float  part[1024][1024]: per-block u partials            (4 MB)
//
// d_out layout: [0:512) out fp32 | [512:33280) attention2 as 0.0/1.0

// ---------------------------------------------------------------------------
// K1: one wave per k (1024 waves). No atomics, no zeroing (k2b overwrites u16).
// ---------------------------------------------------------------------------
__global__ __launch_bounds__(256) void k1_prep(const float* __restrict__ W,
                                               const float* __restrict__ a,
                                               const float* __restrict__ h,
                                               float* __restrict__ v,
                                               double* __restrict__ hpart) {
    const int k    = (blockIdx.x * blockDim.x + threadIdx.x) >> 6;  // 0..1023
    const int lane = threadIdx.x & 63;

    const float4* Wrow = (const float4*)(W + (size_t)k * FOUT);
    float4 w0 = Wrow[lane];
    float4 w1 = Wrow[64 + lane];

    const float4* a4 = (const float4*)a;
    float4 a1_0 = a4[lane];
    float4 a1_1 = a4[64 + lane];
    float4 a2_0 = a4[128 + lane];
    float4 a2_1 = a4[192 + lane];

    double d1 = (double)w0.x * a1_0.x + (double)w0.y * a1_0.y +
                (double)w0.z * a1_0.z + (double)w0.w * a1_0.w +
                (double)w1.x * a1_1.x + (double)w1.y * a1_1.y +
                (double)w1.z * a1_1.z + (double)w1.w * a1_1.w;
    double d2 = (double)w0.x * a2_0.x + (double)w0.y * a2_0.y +
                (double)w0.z * a2_0.z + (double)w0.w * a2_0.w +
                (double)w1.x * a2_1.x + (double)w1.y * a2_1.y +
                (double)w1.z * a2_1.z + (double)w1.w * a2_1.w;

    #pragma unroll
    for (int off = 32; off; off >>= 1) {
        d1 += __shfl_xor(d1, off);
        d2 += __shfl_xor(d2, off);
    }
    if (lane == 0) {
        v[k]     = (float)d2;
        hpart[k] = (double)h[k] * d1;
    }
}

// ---------------------------------------------------------------------------
// K2: 1024 blocks x 256 threads (4096 waves, 8 rows/wave). Single adj pass.
// ROUND 7: row-granularity double-buffer to cross the 128-VGPR occupancy
// cliff STRUCTURALLY (no __launch_bounds__ min-waves — R2 showed it clamps
// to 64 + spills). Buffers shrink 128->32 VGPR (A[4]/B[4], one row each,
// prefetch row r+2 when buffer r is consumed). Target ~110 VGPR ->
// 4 waves/SIMD (was 2 since R1) -> 2x stall overlap -> memory duty ~0.6.
// Probe (R6) proved this pattern sustains 6.7 TB/s when not stall-starved.
// Every per-row f64 expression tree, butterfly pairing (32->1), and
// zacc/uacc/e accumulation order is unchanged -> bitwise-identical outputs.
// ---------------------------------------------------------------------------
__global__ __launch_bounds__(256) void k2_main(const float* __restrict__ adj,
                                               const float* __restrict__ v,
                                               const double* __restrict__ hpart,
                                               double* __restrict__ e,
                                               float* __restrict__ part,  // [1024][1024]
                                               double* __restrict__ zpart) {
    __shared__ float  uls[4][1024];
    __shared__ double zls[4];

    const int wave  = threadIdx.x >> 6;               // 0..3
    const int lane  = threadIdx.x & 63;
    const int gwave = blockIdx.x * 4 + wave;          // 0..4095

    const int row0 = gwave * 8;
    // per-lane base; row stride = FIN/4 = 256 float4s
    const float4* base = (const float4*)(adj + (size_t)row0 * FIN) + lane;

    float4 A[4], B[4];   // one row each (16 VGPR apiece)

    // preload row 0 -> A, row 1 -> B (8 loads in flight)
    #pragma unroll
    for (int q = 0; q < 4; ++q) A[q] = base[q * 64];
    #pragma unroll
    for (int q = 0; q < 4; ++q) B[q] = base[256 + q * 64];

    // c0 = sum(hpart), identical order in every wave -> bitwise-identical
    // (computed while the adj loads are in flight)
    double c0 = 0.0;
    #pragma unroll
    for (int j = 0; j < 16; ++j) c0 += hpart[j * 64 + lane];
    #pragma unroll
    for (int off = 32; off; off >>= 1) c0 += __shfl_xor(c0, off);

    const float4* v4 = (const float4*)v;
    float4 vf[4];
    #pragma unroll
    for (int q = 0; q < 4; ++q) vf[q] = v4[q * 64 + lane];

    float  uacc[4][4] = {};
    double zacc = 0.0;   // wave-uniform

    // process ONE row held in buf (r = compile-time literal at each call
    // site -> prefetch condition and e-index fold); prefetch row r+2
    auto do_row = [&](float4 (&buf)[4], const int r) {
        // --- dot: same 16-element per-lane chain as all prior rounds
        double dot = 0.0;
        #pragma unroll
        for (int q = 0; q < 4; ++q) {
            dot += (double)buf[q].x * vf[q].x + (double)buf[q].y * vf[q].y +
                   (double)buf[q].z * vf[q].z + (double)buf[q].w * vf[q].w;
        }
        // --- same 32->1 butterfly pairing
        #pragma unroll
        for (int off = 32; off; off >>= 1) dot += __shfl_xor(dot, off);

        double s = c0 + dot;
        if (s < 0.0) s *= 0.1;           // leaky_relu(0.1)
        const double ev = exp(s);        // wave-uniform
        zacc += ev;                      // ascending row order (unchanged)
        if (lane == 0) e[row0 + r] = ev;

        const float evf = (float)ev;
        #pragma unroll
        for (int q = 0; q < 4; ++q) {    // same q, x,y,z,w order
            uacc[q][0] += evf * buf[q].x;
            uacc[q][1] += evf * buf[q].y;
            uacc[q][2] += evf * buf[q].z;
            uacc[q][3] += evf * buf[q].w;
        }

        // buf is dead: prefetch row r+2 (in flight during next row's compute)
        if (r + 2 < 8) {
            #pragma unroll
            for (int q = 0; q < 4; ++q) buf[q] = base[(r + 2) * 256 + q * 64];
        }
    };

    do_row(A, 0); do_row(B, 1);
    do_row(A, 2); do_row(B, 3);
    do_row(A, 4); do_row(B, 5);
    do_row(A, 6); do_row(B, 7);

    // per-wave u partial -> LDS (conflict-free b128 writes)
    float4* uls4w = (float4*)&uls[wave][0];
    #pragma unroll
    for (int q = 0; q < 4; ++q)
        uls4w[q * 64 + lane] = make_float4(uacc[q][0], uacc[q][1], uacc[q][2], uacc[q][3]);

    if (lane == 0) zls[wave] = zacc;   // zacc already wave-complete

    __syncthreads();

    // cross-wave reduce; thread t owns cols 4t..4t+3
    const int t = threadIdx.x;
    const float4* uls4 = (const float4*)uls;
    float4 s0 = uls4[t];
    float4 s1 = uls4[256 + t];
    float4 s2 = uls4[512 + t];
    float4 s3 = uls4[768 + t];

    // privatized block partial: one coalesced float4 store, NO atomics
    float4* prow = (float4*)(part + (size_t)blockIdx.x * 1024);
    prow[t] = make_float4(s0.x + s1.x + s2.x + s3.x,
                          s0.y + s1.y + s2.y + s3.y,
                          s0.z + s1.z + s2.z + s3.z,
                          s0.w + s1.w + s2.w + s3.w);

    if (t == 0) zpart[blockIdx.x] = zls[0] + zls[1] + zls[2] + zls[3];
}

// ---------------------------------------------------------------------------
// K2b: reduce part[1024][1024] -> u16[16][1024]. 64 blocks x 256 threads.
// ---------------------------------------------------------------------------
__global__ __launch_bounds__(256) void k2b_reduce(const float* __restrict__ part,
                                                  float* __restrict__ u16) {
    const int g   = blockIdx.x >> 2;          // 0..15
    const int c   = blockIdx.x & 3;           // 0..3
    const int col = c * 256 + threadIdx.x;    // 0..1023
    const float* p = part + (size_t)g * 64 * 1024 + col;
    float acc = 0.f;
    #pragma unroll 8
    for (int b = 0; b < 64; ++b) acc += p[(size_t)b * 1024];
    u16[g * 1024 + col] = acc;
}

// ---------------------------------------------------------------------------
// Deterministic Z from zpart (identical order in every block).
// ---------------------------------------------------------------------------
__device__ __forceinline__ double block_reduce_Z(const double* __restrict__ zpart,
                                                 double* zs) {
    const int t = threadIdx.x;
    zs[t] = zpart[t] + zpart[256 + t] + zpart[512 + t] + zpart[768 + t];
    __syncthreads();
    for (int st = 128; st > 0; st >>= 1) {
        if (t < st) zs[t] += zs[t + st];
        __syncthreads();
    }
    double Z = zs[0];
    __syncthreads();
    return Z;
}

// ---------------------------------------------------------------------------
// K3 (fused): blocks 0..15  -> out[0:512] = (u/Z) @ W1
//             blocks 16..31 -> out[512+i] = (N*e_i > Z) ? 1 : 0
// ---------------------------------------------------------------------------
__global__ __launch_bounds__(256) void k3_final(const double* __restrict__ e,
                                                const double* __restrict__ zpart,
                                                const float* __restrict__ u16,
                                                const float* __restrict__ W1,
                                                float* __restrict__ out) {
    __shared__ double zs[256];
    const double Z = block_reduce_Z(zpart, zs);
    const int t = threadIdx.x;

    if (blockIdx.x < 16) {
        __shared__ float us[1024];
        __shared__ float red[8][32];

        #pragma unroll
        for (int g = 0; g < 4; ++g) {
            const int k = g * 256 + t;
            float s = 0.f;
            #pragma unroll
            for (int rep = 0; rep < NREP; ++rep) s += u16[rep * 1024 + k];
            us[k] = s;
        }
        __syncthreads();

        const int cl  = t & 31;
        const int kg  = t >> 5;
        const int col = blockIdx.x * 32 + cl;
        float acc = 0.f;
        #pragma unroll 8
        for (int kk = 0; kk < 128; ++kk) {
            const int k = kg * 128 + kk;
            acc += us[k] * W1[(size_t)k * FOUT + col];
        }
        red[kg][cl] = acc;
        __syncthreads();
        if (t < 32) {
            float tot = 0.f;
            #pragma unroll
            for (int g = 0; g < 8; ++g) tot += red[g][t];
            out[blockIdx.x * 32 + t] = (float)((double)tot / Z);
        }
    } else {
        const int i0 = (blockIdx.x - 16) * 2048 + t * 8;
        const double2* e2 = (const double2*)(e + i0);
        const double thr = Z;
        float r[8];
        #pragma unroll
        for (int q = 0; q < 4; ++q) {
            double2 ev = e2[q];
            r[2 * q]     = (ev.x * (double)NROWS > thr) ? 1.0f : 0.0f;
            r[2 * q + 1] = (ev.y * (double)NROWS > thr) ? 1.0f : 0.0f;
        }
        float4* o4 = (float4*)(out + FOUT + i0);
        o4[0] = make_float4(r[0], r[1], r[2], r[3]);
        o4[1] = make_float4(r[4], r[5], r[6], r[7]);
    }
}

extern "C" void kernel_launch(void* const* d_in, const int* in_sizes, int n_in,
                              void* d_out, int out_size, void* d_ws, size_t ws_size,
                              hipStream_t stream) {
    const float* h   = (const float*)d_in[0];   // (1, 1024)
    const float* adj = (const float*)d_in[1];   // (32768, 1024)
    const float* W   = (const float*)d_in[2];   // (1024, 512)
    const float* a   = (const float*)d_in[3];   // (1024, 1)
    const float* W1  = (const float*)d_in[4];   // (1024, 512)
    float* out = (float*)d_out;

    double* e     = (double*)d_ws;              // [32768]
    double* hpart = e + NROWS;                  // [1024]
    double* zpart = hpart + 1024;               // [1024]
    float*  v     = (float*)(zpart + 1024);     // [1024]
    float*  u16   = v + 1024;                   // [16][1024]
    float*  part  = u16 + 16 * 1024;            // [1024][1024]

    k1_prep<<<dim3(256),  dim3(256), 0, stream>>>(W, a, h, v, hpart);
    k2_main<<<dim3(1024), dim3(256), 0, stream>>>(adj, v, hpart, e, part, zpart);
    k2b_reduce<<<dim3(64), dim3(256), 0, stream>>>(part, u16);
    k3_final<<<dim3(32),  dim3(256), 0, stream>>>(e, zpart, u16, W1, out);
}